// Round 1
// baseline (576.506 us; speedup 1.0000x reference)
//
#include <hip/hip_runtime.h>
#include <math.h>

// Problem constants
constexpr int DIM    = 2048;
constexpr int NEXP   = 64;
constexpr int TOPK   = 8;
constexpr int T_TOT  = 32768;        // 4 * 8192 tokens

// Tiling
constexpr int TTILE  = 64;           // tokens per block
constexpr int BK     = 32;           // k-chunk
constexpr int XST    = 66;           // LDS stride (doubles) for k-major W/X tiles (64 + 2 pad, even for 16B align)
constexpr int SST    = 68;           // LDS stride (floats) for scores [e][t]

// Output layout (all float32, concatenated in reference return order)
constexpr size_t OFF_W   = 0;                      // top_w   [T,8]
constexpr size_t OFF_IDX = (size_t)T_TOT * TOPK;   // top_idx [T,8] (as float)
constexpr size_t OFF_B   = OFF_IDX * 2;            // new_adaptive_bias [64]
constexpr size_t OFF_U   = OFF_B + NEXP;           // new_expert_usage  [64]

__global__ __launch_bounds__(256, 2)
void moe_gate_main(const float* __restrict__ x,
                   const float* __restrict__ gw,
                   const float* __restrict__ bias,
                   float* __restrict__ out,
                   unsigned int* __restrict__ cnt)
{
    // staging buffers (doubles) later reused as score matrix (floats)
    __shared__ double smem[2 * BK * XST];          // 33792 B
    __shared__ unsigned int hist[NEXP];

    const int tid = threadIdx.x;
    const int t0  = blockIdx.x * TTILE;
    const int eg  = tid & 15;    // expert group: experts 4*eg .. 4*eg+3
    const int tg  = tid >> 4;    // token group : tokens  4*tg .. 4*tg+3

    if (tid < NEXP) hist[tid] = 0;

    double acc[4][4];
    #pragma unroll
    for (int i = 0; i < 4; ++i)
        #pragma unroll
        for (int j = 0; j < 4; ++j) acc[i][j] = 0.0;

    double* Wd = smem;                 // [BK][XST] k-major, experts contiguous
    double* Xd = smem + BK * XST;      // [BK][XST] k-major, tokens contiguous

    for (int k0 = 0; k0 < DIM; k0 += BK) {
        __syncthreads();
        // Stage: 64 rows x 32 k for both W and X; 512 float4 each, 2 per thread
        #pragma unroll
        for (int s = 0; s < 2; ++s) {
            const int f = tid + s * 256;           // float4 index 0..511
            const int r = f >> 3;                  // row (expert / token) 0..63
            const int c = (f & 7) << 2;            // k offset 0,4,...,28
            const float4 wv = *reinterpret_cast<const float4*>(gw + (size_t)r * DIM + k0 + c);
            const float4 xv = *reinterpret_cast<const float4*>(x + (size_t)(t0 + r) * DIM + k0 + c);
            Wd[(c + 0) * XST + r] = (double)wv.x;
            Wd[(c + 1) * XST + r] = (double)wv.y;
            Wd[(c + 2) * XST + r] = (double)wv.z;
            Wd[(c + 3) * XST + r] = (double)wv.w;
            Xd[(c + 0) * XST + r] = (double)xv.x;
            Xd[(c + 1) * XST + r] = (double)xv.y;
            Xd[(c + 2) * XST + r] = (double)xv.z;
            Xd[(c + 3) * XST + r] = (double)xv.w;
        }
        __syncthreads();

        #pragma unroll 4
        for (int k = 0; k < BK; ++k) {
            const double* wp = Wd + k * XST + 4 * eg;
            const double* xp = Xd + k * XST + 4 * tg;
            const double w0 = wp[0], w1 = wp[1], w2 = wp[2], w3 = wp[3];
            const double x0 = xp[0], x1 = xp[1], x2 = xp[2], x3 = xp[3];
            acc[0][0] = fma(w0, x0, acc[0][0]);
            acc[0][1] = fma(w0, x1, acc[0][1]);
            acc[0][2] = fma(w0, x2, acc[0][2]);
            acc[0][3] = fma(w0, x3, acc[0][3]);
            acc[1][0] = fma(w1, x0, acc[1][0]);
            acc[1][1] = fma(w1, x1, acc[1][1]);
            acc[1][2] = fma(w1, x2, acc[1][2]);
            acc[1][3] = fma(w1, x3, acc[1][3]);
            acc[2][0] = fma(w2, x0, acc[2][0]);
            acc[2][1] = fma(w2, x1, acc[2][1]);
            acc[2][2] = fma(w2, x2, acc[2][2]);
            acc[2][3] = fma(w2, x3, acc[2][3]);
            acc[3][0] = fma(w3, x0, acc[3][0]);
            acc[3][1] = fma(w3, x1, acc[3][1]);
            acc[3][2] = fma(w3, x2, acc[3][2]);
            acc[3][3] = fma(w3, x3, acc[3][3]);
        }
    }

    __syncthreads();
    // Dump scores (+ adaptive bias) to LDS transposed: S[e][t], float
    float* S = reinterpret_cast<float*>(smem);
    #pragma unroll
    for (int ei = 0; ei < 4; ++ei) {
        const int e = 4 * eg + ei;
        const float b = bias[e];
        float4 v;
        v.x = (float)acc[ei][0] + b;
        v.y = (float)acc[ei][1] + b;
        v.z = (float)acc[ei][2] + b;
        v.w = (float)acc[ei][3] + b;
        *reinterpret_cast<float4*>(S + e * SST + 4 * tg) = v;
    }
    __syncthreads();

    if (tid < TTILE) {
        const int t = tid;
        float bv[TOPK];
        int   bi[TOPK];
        #pragma unroll
        for (int j = 0; j < TOPK; ++j) { bv[j] = -INFINITY; bi[j] = 0; }

        // top-8 (descending, lowest index first on ties — strict '>' everywhere)
        for (int e = 0; e < NEXP; ++e) {
            const float v = S[e * SST + t];
            if (v > bv[TOPK - 1]) {
                bv[TOPK - 1] = v; bi[TOPK - 1] = e;
                #pragma unroll
                for (int j = TOPK - 1; j > 0; --j) {
                    if (bv[j] > bv[j - 1]) {
                        const float tv = bv[j]; bv[j] = bv[j - 1]; bv[j - 1] = tv;
                        const int   ti = bi[j]; bi[j] = bi[j - 1]; bi[j - 1] = ti;
                    }
                }
            }
        }

        // full softmax denominator over all 64 experts
        const float m = bv[0];
        float Z = 0.0f;
        for (int e = 0; e < NEXP; ++e) Z += expf(S[e * SST + t] - m);
        const float rZ = 1.0f / Z;

        float p[TOPK];
        float ws = 0.0f;
        #pragma unroll
        for (int j = 0; j < TOPK; ++j) { p[j] = expf(bv[j] - m) * rZ; ws += p[j]; }
        const float rd = 1.0f / (ws + 1e-8f);

        const size_t tglob = (size_t)(t0 + t);
        float4 w0 = { p[0] * rd, p[1] * rd, p[2] * rd, p[3] * rd };
        float4 w1 = { p[4] * rd, p[5] * rd, p[6] * rd, p[7] * rd };
        *reinterpret_cast<float4*>(out + OFF_W + tglob * TOPK)     = w0;
        *reinterpret_cast<float4*>(out + OFF_W + tglob * TOPK + 4) = w1;
        float4 i0 = { (float)bi[0], (float)bi[1], (float)bi[2], (float)bi[3] };
        float4 i1 = { (float)bi[4], (float)bi[5], (float)bi[6], (float)bi[7] };
        *reinterpret_cast<float4*>(out + OFF_IDX + tglob * TOPK)     = i0;
        *reinterpret_cast<float4*>(out + OFF_IDX + tglob * TOPK + 4) = i1;

        #pragma unroll
        for (int j = 0; j < TOPK; ++j) atomicAdd(&hist[bi[j]], 1u);
    }

    __syncthreads();
    if (tid < NEXP) atomicAdd(cnt + tid, hist[tid]);
}

__global__ void moe_gate_fin(const unsigned int* __restrict__ cnt,
                             const float* __restrict__ bias,
                             const float* __restrict__ eu,
                             float* __restrict__ out)
{
    const int e = threadIdx.x;
    const float usage = (float)cnt[e] * (1.0f / (float)(T_TOT * TOPK));
    out[OFF_B + e] = bias[e] - 0.01f * (usage - 1.0f / (float)NEXP);
    out[OFF_U + e] = 0.9f * eu[e] + 0.1f * usage;
}

extern "C" void kernel_launch(void* const* d_in, const int* in_sizes, int n_in,
                              void* d_out, int out_size, void* d_ws, size_t ws_size,
                              hipStream_t stream) {
    const float* x    = (const float*)d_in[0];
    const float* gw   = (const float*)d_in[1];
    const float* bias = (const float*)d_in[2];
    const float* eu   = (const float*)d_in[3];
    float* out = (float*)d_out;
    unsigned int* cnt = (unsigned int*)d_ws;

    hipMemsetAsync(cnt, 0, NEXP * sizeof(unsigned int), stream);
    moe_gate_main<<<T_TOT / TTILE, 256, 0, stream>>>(x, gw, bias, out, cnt);
    moe_gate_fin<<<1, NEXP, 0, stream>>>(cnt, bias, eu, out);
}